// Round 11
// baseline (168.775 us; speedup 1.0000x reference)
//
#include <hip/hip_runtime.h>
#include <math.h>

#define HID 1536
#define NEXP 8
#define NF4 (HID / 4)            // 384 float4 per row
#define TOKS_PER_BLOCK 32        // 4 waves * 8 tokens/wave

// Weights staged once to 48KB LDS (lgkmcnt path). hs is the ONLY vmcnt
// traffic: explicit 2-deep double-buffer (named register arrays, static
// indexing) keeps 12 x 1KB-coalesced hs loads in flight while the previous
// chunk's FMAs run off LDS. __launch_bounds__(256,2) -> VGPR cap 256 (the
// R7-R9 (,8) variant capped VGPR at 64 and forced spills - the bug).
// Per wave: q=lane&15 H-slice, tg=lane>>4, tokens tA=base+tg, tB=base+tg+4.
__global__ __launch_bounds__(256, 2) void router_topk_kernel(
    const float* __restrict__ hs,
    const float* __restrict__ wgt,
    const float* __restrict__ bias,
    float* __restrict__ out,
    int T)
{
    __shared__ float4 wlds[NEXP * NF4];   // 48 KB

    const int tid = threadIdx.x;

    // Stage weights global -> LDS (3072 float4 / 256 thr = 12 each).
    const float4* wg4 = reinterpret_cast<const float4*>(wgt);
    #pragma unroll
    for (int i = 0; i < (NEXP * NF4) / 256; ++i)
        wlds[tid + i * 256] = wg4[tid + i * 256];
    __syncthreads();

    const int lane = tid & 63;
    const int wid  = tid >> 6;
    const int q    = lane & 15;
    const int tg   = lane >> 4;
    const int base = blockIdx.x * TOKS_PER_BLOCK + wid * 8;
    const int tA   = base + tg;
    const int tB   = base + tg + 4;

    const float4* rowA = reinterpret_cast<const float4*>(hs) + (size_t)tA * NF4;
    const float4* rowB = reinterpret_cast<const float4*>(hs) + (size_t)tB * NF4;

    float accA[NEXP], accB[NEXP];
    #pragma unroll
    for (int e = 0; e < NEXP; ++e) { accA[e] = 0.0f; accB[e] = 0.0f; }

    // Two named buffer sets; all indices compile-time (rule #20).
    float4 pA[6], pB[6], nA[6], nB[6];

#define LOADC(BA, BB, C)                                    \
    _Pragma("unroll")                                       \
    for (int j = 0; j < 6; ++j) {                           \
        BA[j] = rowA[((C) * 6 + j) * 16 + q];               \
        BB[j] = rowB[((C) * 6 + j) * 16 + q];               \
    }

#define COMPC(BA, BB, C)                                    \
    _Pragma("unroll")                                       \
    for (int j = 0; j < 6; ++j) {                           \
        _Pragma("unroll")                                   \
        for (int e = 0; e < NEXP; ++e) {                    \
            const float4 wv = wlds[e * NF4 + ((C) * 6 + j) * 16 + q]; \
            accA[e] = fmaf(BA[j].x, wv.x, accA[e]);         \
            accA[e] = fmaf(BA[j].y, wv.y, accA[e]);         \
            accA[e] = fmaf(BA[j].z, wv.z, accA[e]);         \
            accA[e] = fmaf(BA[j].w, wv.w, accA[e]);         \
            accB[e] = fmaf(BB[j].x, wv.x, accB[e]);         \
            accB[e] = fmaf(BB[j].y, wv.y, accB[e]);         \
            accB[e] = fmaf(BB[j].z, wv.z, accB[e]);         \
            accB[e] = fmaf(BB[j].w, wv.w, accB[e]);         \
        }                                                   \
    }

    LOADC(pA, pB, 0)          // chunk 0 in flight
    LOADC(nA, nB, 1)          // chunk 1 in flight (2-deep)
    COMPC(pA, pB, 0)          // waits only chunk 0's 12 loads
    LOADC(pA, pB, 2)          // refill
    COMPC(nA, nB, 1)
    LOADC(nA, nB, 3)
    COMPC(pA, pB, 2)
    COMPC(nA, nB, 3)

#undef LOADC
#undef COMPC

    // Butterfly over the 16-lane slice group: full logits on every lane.
    #pragma unroll
    for (int m = 1; m <= 8; m <<= 1) {
        #pragma unroll
        for (int e = 0; e < NEXP; ++e) {
            accA[e] += __shfl_xor(accA[e], m, 64);
            accB[e] += __shfl_xor(accB[e], m, 64);
        }
    }

    // scores = sigmoid(logits); choice scores add the correction bias.
    float sA[NEXP], scA[NEXP], sB[NEXP], scB[NEXP];
    #pragma unroll
    for (int e = 0; e < NEXP; ++e) {
        const float be = bias[e];
        sA[e]  = 1.0f / (1.0f + __expf(-accA[e]));
        scA[e] = sA[e] + be;
        sB[e]  = 1.0f / (1.0f + __expf(-accB[e]));
        scB[e] = sB[e] + be;
    }

    // top-2 on sc, lowest-index-first tie-break (matches jax.lax.top_k).
    int   a0 = 0;
    float av0 = scA[0], aw0 = sA[0];
    #pragma unroll
    for (int e = 1; e < NEXP; ++e)
        if (scA[e] > av0) { av0 = scA[e]; aw0 = sA[e]; a0 = e; }
    int   a1 = -1;
    float av1 = -3.4e38f, aw1 = 0.0f;
    #pragma unroll
    for (int e = 0; e < NEXP; ++e)
        if (e != a0 && scA[e] > av1) { av1 = scA[e]; aw1 = sA[e]; a1 = e; }
    const float ainv = 1.0f / (aw0 + aw1 + 1e-20f);

    int   b0 = 0;
    float bv0 = scB[0], bw0 = sB[0];
    #pragma unroll
    for (int e = 1; e < NEXP; ++e)
        if (scB[e] > bv0) { bv0 = scB[e]; bw0 = sB[e]; b0 = e; }
    int   b1 = -1;
    float bv1 = -3.4e38f, bw1 = 0.0f;
    #pragma unroll
    for (int e = 0; e < NEXP; ++e)
        if (e != b0 && scB[e] > bv1) { bv1 = scB[e]; bw1 = sB[e]; b1 = e; }
    const float binv = 1.0f / (bw0 + bw1 + 1e-20f);

    // Lanes q=0/1 write tA's two slots; q=2/3 write tB's.
    if (q < 2 && tA < T) {
        out[tA * 2 + q]         = (q == 0) ? (float)a0 : (float)a1;
        out[T * 2 + tA * 2 + q] = ((q == 0) ? aw0 : aw1) * ainv;
    }
    if (q >= 2 && q < 4 && tB < T) {
        const int p = q - 2;
        out[tB * 2 + p]         = (p == 0) ? (float)b0 : (float)b1;
        out[T * 2 + tB * 2 + p] = ((p == 0) ? bw0 : bw1) * binv;
    }
}

extern "C" void kernel_launch(void* const* d_in, const int* in_sizes, int n_in,
                              void* d_out, int out_size, void* d_ws, size_t ws_size,
                              hipStream_t stream)
{
    const float* hs   = (const float*)d_in[0];   // (4,4096,1536) f32
    const float* wgt  = (const float*)d_in[1];   // (8,1536) f32
    const float* bias = (const float*)d_in[2];   // (8,) f32
    float* out = (float*)d_out;                  // [2T idx | 2T weights] f32

    const int T = in_sizes[0] / HID;             // 16384
    const int blocks = (T + TOKS_PER_BLOCK - 1) / TOKS_PER_BLOCK;  // 512

    // DIAGNOSTIC dual launch (idempotent: every output lane rewrites the
    // same value). Delta-total vs the single-launch R9 run separates
    // warm-kernel time from harness overhead; any dispatch >59us surfaces
    // in the top-5 profile rows. Revert to single launch once decomposed.
    router_topk_kernel<<<blocks, 256, 0, stream>>>(hs, wgt, bias, out, T);
    router_topk_kernel<<<blocks, 256, 0, stream>>>(hs, wgt, bias, out, T);
}

// Round 12
// 150.454 us; speedup vs baseline: 1.1218x; 1.1218x over previous
//
#include <hip/hip_runtime.h>
#include <math.h>

#define HID 1536
#define NEXP 8
#define NF4 (HID / 4)            // 384 float4 per row
#define TOKS_PER_BLOCK 16        // 4 waves * 4 tokens/wave

// 32-lane slice layout: q=lane&31 covers 12 float4 of the row, tg=lane>>5
// picks the token pair (tA=base+tg, tB=base+tg+2) -> 4 tokens/wave,
// 16/block, grid=1024 -> 3 blocks (12 waves) resident per CU under the
// 48KB LDS cap (R4-R11 had grid=512 -> only 2 blocks, 21% occupancy).
// Weights in LDS (lgkmcnt); hs is the sole vmcnt stream, 2-deep named
// double-buffer (6 loads in flight) so FMAs run off LDS while the next
// chunk streams. 2 tokens/lane keeps every weight ds_read feeding 8 FMAs.
__global__ __launch_bounds__(256, 4) void router_topk_kernel(
    const float* __restrict__ hs,
    const float* __restrict__ wgt,
    const float* __restrict__ bias,
    float* __restrict__ out,
    int T)
{
    __shared__ float4 wlds[NEXP * NF4];   // 48 KB

    const int tid = threadIdx.x;

    // Stage weights global -> LDS (3072 float4 / 256 thr = 12 each).
    const float4* wg4 = reinterpret_cast<const float4*>(wgt);
    #pragma unroll
    for (int i = 0; i < (NEXP * NF4) / 256; ++i)
        wlds[tid + i * 256] = wg4[tid + i * 256];
    __syncthreads();

    const int lane = tid & 63;
    const int wid  = tid >> 6;
    const int q    = lane & 31;    // float4 column within 512B row segment
    const int tg   = lane >> 5;    // wave half -> token pair select
    const int base = blockIdx.x * TOKS_PER_BLOCK + wid * 4;
    const int tA   = base + tg;
    const int tB   = base + tg + 2;

    const float4* rowA = reinterpret_cast<const float4*>(hs) + (size_t)tA * NF4;
    const float4* rowB = reinterpret_cast<const float4*>(hs) + (size_t)tB * NF4;

    float accA[NEXP], accB[NEXP];
    #pragma unroll
    for (int e = 0; e < NEXP; ++e) { accA[e] = 0.0f; accB[e] = 0.0f; }

    // Two named buffer sets; all indices compile-time (rule #20).
    // 12 j-steps split into 4 chunks of 3; 2-deep: 6 loads always in flight.
    float4 pA[3], pB[3], nA[3], nB[3];

#define LOADC(BA, BB, C)                                    \
    _Pragma("unroll")                                       \
    for (int j = 0; j < 3; ++j) {                           \
        BA[j] = rowA[((C) * 3 + j) * 32 + q];               \
        BB[j] = rowB[((C) * 3 + j) * 32 + q];               \
    }

#define COMPC(BA, BB, C)                                    \
    _Pragma("unroll")                                       \
    for (int j = 0; j < 3; ++j) {                           \
        _Pragma("unroll")                                   \
        for (int e = 0; e < NEXP; ++e) {                    \
            const float4 wv = wlds[e * NF4 + ((C) * 3 + j) * 32 + q]; \
            accA[e] = fmaf(BA[j].x, wv.x, accA[e]);         \
            accA[e] = fmaf(BA[j].y, wv.y, accA[e]);         \
            accA[e] = fmaf(BA[j].z, wv.z, accA[e]);         \
            accA[e] = fmaf(BA[j].w, wv.w, accA[e]);         \
            accB[e] = fmaf(BB[j].x, wv.x, accB[e]);         \
            accB[e] = fmaf(BB[j].y, wv.y, accB[e]);         \
            accB[e] = fmaf(BB[j].z, wv.z, accB[e]);         \
            accB[e] = fmaf(BB[j].w, wv.w, accB[e]);         \
        }                                                   \
    }

    LOADC(pA, pB, 0)          // chunk 0 in flight
    LOADC(nA, nB, 1)          // chunk 1 in flight (2-deep)
    COMPC(pA, pB, 0)          // waits only chunk 0's 6 loads
    LOADC(pA, pB, 2)          // refill
    COMPC(nA, nB, 1)
    LOADC(nA, nB, 3)
    COMPC(pA, pB, 2)
    COMPC(nA, nB, 3)

#undef LOADC
#undef COMPC

    // Butterfly over the 32-lane slice group (masks 1..16): every lane
    // ends with both tokens' full logits.
    #pragma unroll
    for (int m = 1; m <= 16; m <<= 1) {
        #pragma unroll
        for (int e = 0; e < NEXP; ++e) {
            accA[e] += __shfl_xor(accA[e], m, 64);
            accB[e] += __shfl_xor(accB[e], m, 64);
        }
    }

    // scores = sigmoid(logits); choice scores add the correction bias.
    float sA[NEXP], scA[NEXP], sB[NEXP], scB[NEXP];
    #pragma unroll
    for (int e = 0; e < NEXP; ++e) {
        const float be = bias[e];
        sA[e]  = 1.0f / (1.0f + __expf(-accA[e]));
        scA[e] = sA[e] + be;
        sB[e]  = 1.0f / (1.0f + __expf(-accB[e]));
        scB[e] = sB[e] + be;
    }

    // top-2 on sc, lowest-index-first tie-break (matches jax.lax.top_k).
    int   a0 = 0;
    float av0 = scA[0], aw0 = sA[0];
    #pragma unroll
    for (int e = 1; e < NEXP; ++e)
        if (scA[e] > av0) { av0 = scA[e]; aw0 = sA[e]; a0 = e; }
    int   a1 = -1;
    float av1 = -3.4e38f, aw1 = 0.0f;
    #pragma unroll
    for (int e = 0; e < NEXP; ++e)
        if (e != a0 && scA[e] > av1) { av1 = scA[e]; aw1 = sA[e]; a1 = e; }
    const float ainv = 1.0f / (aw0 + aw1 + 1e-20f);

    int   b0 = 0;
    float bv0 = scB[0], bw0 = sB[0];
    #pragma unroll
    for (int e = 1; e < NEXP; ++e)
        if (scB[e] > bv0) { bv0 = scB[e]; bw0 = sB[e]; b0 = e; }
    int   b1 = -1;
    float bv1 = -3.4e38f, bw1 = 0.0f;
    #pragma unroll
    for (int e = 0; e < NEXP; ++e)
        if (e != b0 && scB[e] > bv1) { bv1 = scB[e]; bw1 = sB[e]; b1 = e; }
    const float binv = 1.0f / (bw0 + bw1 + 1e-20f);

    // Lanes q=0/1 write tA's two slots; q=2/3 write tB's.
    if (q < 2 && tA < T) {
        out[tA * 2 + q]         = (q == 0) ? (float)a0 : (float)a1;
        out[T * 2 + tA * 2 + q] = ((q == 0) ? aw0 : aw1) * ainv;
    }
    if (q >= 2 && q < 4 && tB < T) {
        const int p = q - 2;
        out[tB * 2 + p]         = (p == 0) ? (float)b0 : (float)b1;
        out[T * 2 + tB * 2 + p] = ((p == 0) ? bw0 : bw1) * binv;
    }
}

extern "C" void kernel_launch(void* const* d_in, const int* in_sizes, int n_in,
                              void* d_out, int out_size, void* d_ws, size_t ws_size,
                              hipStream_t stream)
{
    const float* hs   = (const float*)d_in[0];   // (4,4096,1536) f32
    const float* wgt  = (const float*)d_in[1];   // (8,1536) f32
    const float* bias = (const float*)d_in[2];   // (8,) f32
    float* out = (float*)d_out;                  // [2T idx | 2T weights] f32

    const int T = in_sizes[0] / HID;             // 16384
    const int blocks = (T + TOKS_PER_BLOCK - 1) / TOKS_PER_BLOCK;  // 1024
    router_topk_kernel<<<blocks, 256, 0, stream>>>(hs, wgt, bias, out, T);
}